// Round 1
// baseline (3894.463 us; speedup 1.0000x reference)
//
#include <hip/hip_runtime.h>
#include <hip/hip_bf16.h>

#define EPSV 1e-5f

// ---------------------------------------------------------------------------
// Block reduction helpers (256 threads = 4 waves of 64)
// ---------------------------------------------------------------------------
__device__ __forceinline__ float block_sum256(float v, float* red) {
#pragma unroll
    for (int off = 32; off; off >>= 1) v += __shfl_down(v, off);
    int lane = threadIdx.x & 63, w = threadIdx.x >> 6;
    __syncthreads();
    if (lane == 0) red[w] = v;
    __syncthreads();
    return red[0] + red[1] + red[2] + red[3];
}

__device__ __forceinline__ float block_max256(float v, float* red) {
#pragma unroll
    for (int off = 32; off; off >>= 1) v = fmaxf(v, __shfl_down(v, off));
    int lane = threadIdx.x & 63, w = threadIdx.x >> 6;
    __syncthreads();
    if (lane == 0) red[w] = v;
    __syncthreads();
    return fmaxf(fmaxf(red[0], red[1]), fmaxf(red[2], red[3]));
}

// ---------------------------------------------------------------------------
// Row LayerNorm: Y[row, :] = (X[row,:]-mu)*rsqrt(var+eps)*g + b
// D must be a multiple of 4 (here 512 or 1024). One block per row.
// ---------------------------------------------------------------------------
__global__ __launch_bounds__(256)
void ln_rows(const float* __restrict__ X, const float* __restrict__ g,
             const float* __restrict__ b, float* __restrict__ Y, int D) {
    __shared__ float red[4];
    int row = blockIdx.x;
    const float* x = X + (size_t)row * D;
    float* y = Y + (size_t)row * D;
    int tid = threadIdx.x;
    int nvec = D >> 2;

    float s = 0.f, sq = 0.f;
    for (int i = tid; i < nvec; i += 256) {
        float4 v = ((const float4*)x)[i];
        s += v.x + v.y + v.z + v.w;
        sq += v.x * v.x + v.y * v.y + v.z * v.z + v.w * v.w;
    }
    float ts = block_sum256(s, red);
    float tq = block_sum256(sq, red);
    float invD = 1.f / (float)D;
    float mu = ts * invD;
    float var = tq * invD - mu * mu;
    float rstd = rsqrtf(var + EPSV);

    for (int i = tid; i < nvec; i += 256) {
        float4 v = ((const float4*)x)[i];
        float4 gv = ((const float4*)g)[i];
        float4 bv = ((const float4*)b)[i];
        float4 o;
        o.x = (v.x - mu) * rstd * gv.x + bv.x;
        o.y = (v.y - mu) * rstd * gv.y + bv.y;
        o.z = (v.z - mu) * rstd * gv.z + bv.z;
        o.w = (v.w - mu) * rstd * gv.w + bv.w;
        ((float4*)y)[i] = o;
    }
}

// ---------------------------------------------------------------------------
// FP32 tiled GEMM: C_tile = A[M,K] @ B[K,N] (+bias, +relu, +residual per MODE)
// MODE 0: C = relu(A@B + bias)
// MODE 1: C = C + relu(A@B + bias)   (residual update in place)
// MODE 2: C = A@B + bias
// 128x128 tile, 256 threads, 8x8 per thread, BK=16. M%128==0, N%128==0, K%16==0.
// ---------------------------------------------------------------------------
#define TILE 128
#define BK 16
#define APAD 132   // padded LDS row stride for A (132*4 bytes, 16B-aligned rows)

template <int MODE>
__global__ __launch_bounds__(256)
void gemm_tile(const float* __restrict__ A, const float* __restrict__ B,
               const float* __restrict__ bias, float* __restrict__ C,
               int M, int N, int K) {
    __shared__ float As[BK][APAD];
    __shared__ float Bs[BK][TILE];

    int tid = threadIdx.x;
    int tx = tid & 15;   // n sub-tile 0..15
    int ty = tid >> 4;   // m sub-tile 0..15
    int m0 = blockIdx.x * TILE;
    int n0 = blockIdx.y * TILE;

    // A loader: each thread 2x float4 (rows la_m, la_m+64; cols la_k..la_k+3)
    int la_m = tid >> 2;
    int la_k = (tid & 3) << 2;
    // B loader: each thread 2x float4 (rows lb_k, lb_k+8; cols lb_n..lb_n+3)
    int lb_k = tid >> 5;
    int lb_n = (tid & 31) << 2;

    float acc[8][8] = {};

    for (int k0 = 0; k0 < K; k0 += BK) {
        float4 a0 = *(const float4*)&A[(size_t)(m0 + la_m) * K + k0 + la_k];
        float4 a1 = *(const float4*)&A[(size_t)(m0 + la_m + 64) * K + k0 + la_k];
        float4 b0 = *(const float4*)&B[(size_t)(k0 + lb_k) * N + n0 + lb_n];
        float4 b1 = *(const float4*)&B[(size_t)(k0 + lb_k + 8) * N + n0 + lb_n];
        __syncthreads();   // previous iteration's LDS reads done
        As[la_k + 0][la_m] = a0.x;
        As[la_k + 1][la_m] = a0.y;
        As[la_k + 2][la_m] = a0.z;
        As[la_k + 3][la_m] = a0.w;
        As[la_k + 0][la_m + 64] = a1.x;
        As[la_k + 1][la_m + 64] = a1.y;
        As[la_k + 2][la_m + 64] = a1.z;
        As[la_k + 3][la_m + 64] = a1.w;
        *(float4*)&Bs[lb_k][lb_n] = b0;
        *(float4*)&Bs[lb_k + 8][lb_n] = b1;
        __syncthreads();

#pragma unroll
        for (int kk = 0; kk < BK; ++kk) {
            float a_[8], b_[8];
            *(float4*)&a_[0] = *(const float4*)&As[kk][ty * 8];
            *(float4*)&a_[4] = *(const float4*)&As[kk][ty * 8 + 4];
            *(float4*)&b_[0] = *(const float4*)&Bs[kk][tx * 8];
            *(float4*)&b_[4] = *(const float4*)&Bs[kk][tx * 8 + 4];
#pragma unroll
            for (int i = 0; i < 8; ++i)
#pragma unroll
                for (int j = 0; j < 8; ++j)
                    acc[i][j] = fmaf(a_[i], b_[j], acc[i][j]);
        }
    }

    // epilogue
    float bv[8];
    *(float4*)&bv[0] = *(const float4*)&bias[n0 + tx * 8];
    *(float4*)&bv[4] = *(const float4*)&bias[n0 + tx * 8 + 4];
#pragma unroll
    for (int i = 0; i < 8; ++i) {
        size_t row = (size_t)(m0 + ty * 8 + i);
        float* cp = &C[row * N + n0 + tx * 8];
        float out[8];
#pragma unroll
        for (int j = 0; j < 8; ++j) {
            float c = acc[i][j] + bv[j];
            if (MODE == 0) c = fmaxf(c, 0.f);
            out[j] = c;
        }
        if (MODE == 1) {
            float4 o0 = *(const float4*)&cp[0];
            float4 o1 = *(const float4*)&cp[4];
            out[0] = o0.x + fmaxf(out[0], 0.f);
            out[1] = o0.y + fmaxf(out[1], 0.f);
            out[2] = o0.z + fmaxf(out[2], 0.f);
            out[3] = o0.w + fmaxf(out[3], 0.f);
            out[4] = o1.x + fmaxf(out[4], 0.f);
            out[5] = o1.y + fmaxf(out[5], 0.f);
            out[6] = o1.z + fmaxf(out[6], 0.f);
            out[7] = o1.w + fmaxf(out[7], 0.f);
        }
        *(float4*)&cp[0] = *(float4*)&out[0];
        *(float4*)&cp[4] = *(float4*)&out[4];
    }
}

// ---------------------------------------------------------------------------
// Fused attention-over-time. One block (256 threads) per (bs, o) pair.
// thread tid == time index l. Computes:
//   mean over l, LN over 257, @Wa1+relu, LN over 256, @Wa2, softmax over l,
//   out[bs,o] = sum_l fc[bs,l,o] * p[l]
// ---------------------------------------------------------------------------
__global__ __launch_bounds__(256)
void attn_fused(const float* __restrict__ fc,
                const float* __restrict__ ln1_g, const float* __restrict__ ln1_b,
                const float* __restrict__ Wa1, const float* __restrict__ ba1,
                const float* __restrict__ ln2_g, const float* __restrict__ ln2_b,
                const float* __restrict__ Wa2, const float* __restrict__ ba2,
                float* __restrict__ out) {
    __shared__ float tn[256];
    __shared__ float an[256];
    __shared__ float red[4];

    int bs = blockIdx.x >> 7;
    int o = blockIdx.x & 127;
    int tid = threadIdx.x;

    float v = fc[(size_t)(bs * 256 + tid) * 128 + o];

    // mean over time (the 257th element of t)
    float s256 = block_sum256(v, red);
    float sq256 = block_sum256(v * v, red);
    float meanv = s256 * (1.f / 256.f);

    // LN over the 257-vector [v_0..v_255, meanv]
    float ts = s256 + meanv;
    float tq = sq256 + meanv * meanv;
    float mu = ts * (1.f / 257.f);
    float var = tq * (1.f / 257.f) - mu * mu;
    float rstd = rsqrtf(var + EPSV);
    tn[tid] = (v - mu) * rstd * ln1_g[tid] + ln1_b[tid];
    float tn256 = (meanv - mu) * rstd * ln1_g[256] + ln1_b[256];
    __syncthreads();

    // a[j] = relu(tn . Wa1[:, j] + ba1[j]),  j = tid
    float acc = ba1[tid] + tn256 * Wa1[256 * 256 + tid];
    for (int k = 0; k < 256; ++k) acc = fmaf(tn[k], Wa1[k * 256 + tid], acc);
    acc = fmaxf(acc, 0.f);

    // LN over the 256-vector a
    float s2 = block_sum256(acc, red);
    float q2 = block_sum256(acc * acc, red);
    float mu2 = s2 * (1.f / 256.f);
    float rstd2 = rsqrtf(q2 * (1.f / 256.f) - mu2 * mu2 + EPSV);
    an[tid] = (acc - mu2) * rstd2 * ln2_g[tid] + ln2_b[tid];
    __syncthreads();

    // w[j] = an . Wa2[:, j] + ba2[j]
    float acc2 = ba2[tid];
    for (int k = 0; k < 256; ++k) acc2 = fmaf(an[k], Wa2[k * 256 + tid], acc2);

    // softmax over the 256 w values, then weighted sum with fc column
    float mx = block_max256(acc2, red);
    float e = __expf(acc2 - mx);
    float se = block_sum256(e, red);
    float contrib = v * e / se;
    float total = block_sum256(contrib, red);
    if (tid == 0) out[bs * 128 + o] = total;
}

// ---------------------------------------------------------------------------
// Launch
// ---------------------------------------------------------------------------
extern "C" void kernel_launch(void* const* d_in, const int* in_sizes, int n_in,
                              void* d_out, int out_size, void* d_ws, size_t ws_size,
                              hipStream_t stream) {
    const float* x      = (const float*)d_in[0];
    const float* ln0_g  = (const float*)d_in[1];
    const float* ln0_b  = (const float*)d_in[2];
    const float* W0     = (const float*)d_in[3];
    const float* b0     = (const float*)d_in[4];
    const float* rln_g  = (const float*)d_in[5];
    const float* rln_b  = (const float*)d_in[6];
    const float* rW     = (const float*)d_in[7];
    const float* rb     = (const float*)d_in[8];
    const float* lnf_g  = (const float*)d_in[9];
    const float* lnf_b  = (const float*)d_in[10];
    const float* Wf     = (const float*)d_in[11];
    const float* bf_    = (const float*)d_in[12];
    const float* ln1_g  = (const float*)d_in[13];
    const float* ln1_b  = (const float*)d_in[14];
    const float* Wa1    = (const float*)d_in[15];
    const float* ba1    = (const float*)d_in[16];
    const float* ln2_g  = (const float*)d_in[17];
    const float* ln2_b  = (const float*)d_in[18];
    const float* Wa2    = (const float*)d_in[19];
    const float* ba2    = (const float*)d_in[20];
    float* out = (float*)d_out;

    const int R = 64 * 256;     // 16384 rows
    float* h  = (float*)d_ws;                       // R*1024
    float* hn = h + (size_t)R * 1024;               // R*1024
    float* fc = hn + (size_t)R * 1024;              // R*128

    // stem: h = relu(LN(x) @ W0 + b0)
    ln_rows<<<R, 256, 0, stream>>>(x, ln0_g, ln0_b, hn, 512);
    gemm_tile<0><<<dim3(R / TILE, 1024 / TILE), 256, 0, stream>>>(hn, W0, b0, h, R, 1024, 512);

    // residual blocks
    for (int i = 0; i < 8; ++i) {
        ln_rows<<<R, 256, 0, stream>>>(h, rln_g + i * 1024, rln_b + i * 1024, hn, 1024);
        gemm_tile<1><<<dim3(R / TILE, 1024 / TILE), 256, 0, stream>>>(
            hn, rW + (size_t)i * 1024 * 1024, rb + i * 1024, h, R, 1024, 1024);
    }

    // head: fc = LN(h) @ Wf + bf
    ln_rows<<<R, 256, 0, stream>>>(h, lnf_g, lnf_b, hn, 1024);
    gemm_tile<2><<<dim3(R / TILE, 128 / TILE), 256, 0, stream>>>(hn, Wf, bf_, fc, R, 128, 1024);

    // fused attention + weighted sum
    attn_fused<<<64 * 128, 256, 0, stream>>>(fc, ln1_g, ln1_b, Wa1, ba1,
                                             ln2_g, ln2_b, Wa2, ba2, out);
}

// Round 2
// 1442.032 us; speedup vs baseline: 2.7007x; 2.7007x over previous
//
#include <hip/hip_runtime.h>
#include <hip/hip_bf16.h>
#include <stdint.h>

#define EPSV 1e-5f

typedef __bf16 bf16x8 __attribute__((ext_vector_type(8)));
typedef float f32x4 __attribute__((ext_vector_type(4)));

// ---------------------------------------------------------------------------
// round-to-nearest bf16 split: f = hi + lo (both bf16), |f-(hi+lo)| ~ 2^-18 |f|
// ---------------------------------------------------------------------------
__device__ __forceinline__ void bf16split(float f, ushort& h, ushort& l) {
    union { float f; uint32_t u; } a; a.f = f;
    uint32_t r = a.u + 0x7FFFu + ((a.u >> 16) & 1u);
    h = (ushort)(r >> 16);
    union { uint32_t u; float f; } hf; hf.u = ((uint32_t)h) << 16;
    float lof = f - hf.f;
    union { float f; uint32_t u; } b; b.f = lof;
    uint32_t r2 = b.u + 0x7FFFu + ((b.u >> 16) & 1u);
    l = (ushort)(r2 >> 16);
}

__device__ __forceinline__ void gload_lds16(const void* g, void* l) {
    __builtin_amdgcn_global_load_lds(
        (const __attribute__((address_space(1))) uint32_t*)g,
        (__attribute__((address_space(3))) uint32_t*)l, 16, 0, 0);
}

// ---------------------------------------------------------------------------
// Block reduction helpers (256 threads = 4 waves of 64)
// ---------------------------------------------------------------------------
__device__ __forceinline__ float block_sum256(float v, float* red) {
#pragma unroll
    for (int off = 32; off; off >>= 1) v += __shfl_down(v, off);
    int lane = threadIdx.x & 63, w = threadIdx.x >> 6;
    __syncthreads();
    if (lane == 0) red[w] = v;
    __syncthreads();
    return red[0] + red[1] + red[2] + red[3];
}

__device__ __forceinline__ float block_max256(float v, float* red) {
#pragma unroll
    for (int off = 32; off; off >>= 1) v = fmaxf(v, __shfl_down(v, off));
    int lane = threadIdx.x & 63, w = threadIdx.x >> 6;
    __syncthreads();
    if (lane == 0) red[w] = v;
    __syncthreads();
    return fmaxf(fmaxf(red[0], red[1]), fmaxf(red[2], red[3]));
}

// ---------------------------------------------------------------------------
// Row LayerNorm -> packed hi/lo bf16 output.
// Packed layout: Ap[row][kt][half][km]  (ushort), kt = k/32, km = k%32,
// half 0 = hi, 1 = lo. Row stride = D*2 ushorts = D*4 bytes.
// ---------------------------------------------------------------------------
__global__ __launch_bounds__(256)
void ln_pack(const float* __restrict__ X, const float* __restrict__ g,
             const float* __restrict__ b, ushort* __restrict__ Ap, int D) {
    __shared__ float red[4];
    int row = blockIdx.x;
    const float* x = X + (size_t)row * D;
    ushort* ap = Ap + (size_t)row * (D * 2);
    int tid = threadIdx.x;
    int nvec = D >> 2;

    float s = 0.f, sq = 0.f;
    for (int i = tid; i < nvec; i += 256) {
        float4 v = ((const float4*)x)[i];
        s += v.x + v.y + v.z + v.w;
        sq += v.x * v.x + v.y * v.y + v.z * v.z + v.w * v.w;
    }
    float ts = block_sum256(s, red);
    float tq = block_sum256(sq, red);
    float invD = 1.f / (float)D;
    float mu = ts * invD;
    float var = tq * invD - mu * mu;
    float rstd = rsqrtf(var + EPSV);

    for (int i = tid; i < nvec; i += 256) {
        float4 v = ((const float4*)x)[i];
        float4 gv = ((const float4*)g)[i];
        float4 bv = ((const float4*)b)[i];
        float o[4];
        o[0] = (v.x - mu) * rstd * gv.x + bv.x;
        o[1] = (v.y - mu) * rstd * gv.y + bv.y;
        o[2] = (v.z - mu) * rstd * gv.z + bv.z;
        o[3] = (v.w - mu) * rstd * gv.w + bv.w;
        ushort hi[4], lo[4];
#pragma unroll
        for (int j = 0; j < 4; ++j) bf16split(o[j], hi[j], lo[j]);
        int kt = i >> 3;           // (4i)/32
        int km = (i & 7) << 2;     // (4i)%32
        ushort* dst = ap + kt * 64 + km;
        *(ushort4*)dst = *(ushort4*)hi;
        *(ushort4*)(dst + 32) = *(ushort4*)lo;
    }
}

// ---------------------------------------------------------------------------
// Weight convert+transpose: W[K][N] fp32 -> Wp[n][kt][half][km] packed bf16.
// grid = (ceil(N/64), K/32), block = 64.
// ---------------------------------------------------------------------------
__global__ __launch_bounds__(64)
void conv_w(const float* __restrict__ W, ushort* __restrict__ Wp, int K, int N) {
    int n = blockIdx.x * 64 + threadIdx.x;
    int kt = blockIdx.y;
    if (n >= N) return;
    ushort hi[32], lo[32];
#pragma unroll
    for (int j = 0; j < 32; ++j) {
        float f = W[(size_t)(kt * 32 + j) * N + n];
        bf16split(f, hi[j], lo[j]);
    }
    ushort* dst = Wp + (size_t)n * (K * 2) + kt * 64;
    uint4* d = (uint4*)dst;
    const uint4* ph = (const uint4*)hi;
    const uint4* pl = (const uint4*)lo;
    d[0] = ph[0]; d[1] = ph[1]; d[2] = ph[2]; d[3] = ph[3];
    d[4] = pl[0]; d[5] = pl[1]; d[6] = pl[2]; d[7] = pl[3];
}

// ---------------------------------------------------------------------------
// Split-bf16 MFMA GEMM. C = A@B (+bias, relu, residual per MODE), fp32 out.
// A packed [M][K/32][2][32] bf16 (hi/lo), B packed [N][K/32][2][32] bf16.
// 128x128 tile, BK=32, 256 threads (4 waves, 2x2 of 64x64 each).
// LDS rows are 128B (8x16B slots: 4 hi + 4 lo), XOR-swizzled by row&7 via
// pre-swizzled global source (global_load_lds writes lane-linear).
// MODE 0: C = relu(AB + bias); 1: C += relu(AB + bias); 2: C = AB + bias.
// ---------------------------------------------------------------------------
template <int MODE>
__global__ __launch_bounds__(256)
void gemm_mfma(const ushort* __restrict__ Ap, const ushort* __restrict__ Bp,
               const float* __restrict__ bias, float* __restrict__ C,
               int M, int N, int K) {
    __shared__ ushort Ash[128 * 64];   // 128 rows x 128B
    __shared__ ushort Bsh[128 * 64];

    const int tid = threadIdx.x;
    const int lane = tid & 63;
    const int wv = tid >> 6;
    const int wr = wv >> 1, wc = wv & 1;
    const int m0 = blockIdx.x * 128, n0 = blockIdx.y * 128;
    const int ktc = K >> 5;
    const size_t rowB = (size_t)K * 4;   // packed row bytes

    // staging: slot s = i*256+tid; row = s>>3, q = s&7, source chunk q^(row&7)
    int srow[4], sq[4];
#pragma unroll
    for (int i = 0; i < 4; ++i) {
        int s = i * 256 + tid;
        srow[i] = s >> 3;
        sq[i] = (s & 7) ^ (srow[i] & 7);
    }

    f32x4 acc[4][4] = {};

    for (int kt = 0; kt < ktc; ++kt) {
        __syncthreads();   // previous iteration's LDS reads complete
#pragma unroll
        for (int i = 0; i < 4; ++i) {
            const char* sA = (const char*)Ap + (size_t)(m0 + srow[i]) * rowB + kt * 128 + sq[i] * 16;
            const char* sB = (const char*)Bp + (size_t)(n0 + srow[i]) * rowB + kt * 128 + sq[i] * 16;
            gload_lds16(sA, (char*)Ash + (i * 256 + tid) * 16);
            gload_lds16(sB, (char*)Bsh + (i * 256 + tid) * 16);
        }
        __syncthreads();   // drains vmcnt (compiler inserts waitcnt before barrier)

        bf16x8 ah[4], al[4], bh[4], bl[4];
        const int g = lane >> 4;
        const int rr = lane & 15;
#pragma unroll
        for (int t = 0; t < 4; ++t) {
            int rA = wr * 64 + t * 16 + rr;
            const char* baseA = (const char*)Ash + rA * 128;
            ah[t] = *(const bf16x8*)(baseA + ((g ^ (rA & 7)) * 16));
            al[t] = *(const bf16x8*)(baseA + (((g + 4) ^ (rA & 7)) * 16));
            int rBr = wc * 64 + t * 16 + rr;
            const char* baseB = (const char*)Bsh + rBr * 128;
            bh[t] = *(const bf16x8*)(baseB + ((g ^ (rBr & 7)) * 16));
            bl[t] = *(const bf16x8*)(baseB + (((g + 4) ^ (rBr & 7)) * 16));
        }
#pragma unroll
        for (int mi = 0; mi < 4; ++mi)
#pragma unroll
            for (int ni = 0; ni < 4; ++ni) {
                acc[mi][ni] = __builtin_amdgcn_mfma_f32_16x16x32_bf16(ah[mi], bh[ni], acc[mi][ni], 0, 0, 0);
                acc[mi][ni] = __builtin_amdgcn_mfma_f32_16x16x32_bf16(al[mi], bh[ni], acc[mi][ni], 0, 0, 0);
                acc[mi][ni] = __builtin_amdgcn_mfma_f32_16x16x32_bf16(ah[mi], bl[ni], acc[mi][ni], 0, 0, 0);
            }
    }

    // epilogue: C/D layout col = lane&15, row = (lane>>4)*4 + j  [m89/m91]
#pragma unroll
    for (int mi = 0; mi < 4; ++mi) {
        int r = m0 + wr * 64 + mi * 16 + (lane >> 4) * 4;
#pragma unroll
        for (int ni = 0; ni < 4; ++ni) {
            int c = n0 + wc * 64 + ni * 16 + (lane & 15);
            float bv = bias[c];
#pragma unroll
            for (int j = 0; j < 4; ++j) {
                float v = acc[mi][ni][j] + bv;
                float* cp = &C[(size_t)(r + j) * N + c];
                if (MODE == 0) *cp = fmaxf(v, 0.f);
                else if (MODE == 1) *cp = *cp + fmaxf(v, 0.f);
                else *cp = v;
            }
        }
    }
}

// ---------------------------------------------------------------------------
// Fused attention-over-time. One block (256 threads) per (bs, o) pair.
// ---------------------------------------------------------------------------
__global__ __launch_bounds__(256)
void attn_fused(const float* __restrict__ fc,
                const float* __restrict__ ln1_g, const float* __restrict__ ln1_b,
                const float* __restrict__ Wa1, const float* __restrict__ ba1,
                const float* __restrict__ ln2_g, const float* __restrict__ ln2_b,
                const float* __restrict__ Wa2, const float* __restrict__ ba2,
                float* __restrict__ out) {
    __shared__ float tn[256];
    __shared__ float an[256];
    __shared__ float red[4];

    int bs = blockIdx.x >> 7;
    int o = blockIdx.x & 127;
    int tid = threadIdx.x;

    float v = fc[(size_t)(bs * 256 + tid) * 128 + o];

    float s256 = block_sum256(v, red);
    float sq256 = block_sum256(v * v, red);
    float meanv = s256 * (1.f / 256.f);

    float ts = s256 + meanv;
    float tq = sq256 + meanv * meanv;
    float mu = ts * (1.f / 257.f);
    float var = tq * (1.f / 257.f) - mu * mu;
    float rstd = rsqrtf(var + EPSV);
    tn[tid] = (v - mu) * rstd * ln1_g[tid] + ln1_b[tid];
    float tn256 = (meanv - mu) * rstd * ln1_g[256] + ln1_b[256];
    __syncthreads();

    float acc = ba1[tid] + tn256 * Wa1[256 * 256 + tid];
    for (int k = 0; k < 256; ++k) acc = fmaf(tn[k], Wa1[k * 256 + tid], acc);
    acc = fmaxf(acc, 0.f);

    float s2 = block_sum256(acc, red);
    float q2 = block_sum256(acc * acc, red);
    float mu2 = s2 * (1.f / 256.f);
    float rstd2 = rsqrtf(q2 * (1.f / 256.f) - mu2 * mu2 + EPSV);
    an[tid] = (acc - mu2) * rstd2 * ln2_g[tid] + ln2_b[tid];
    __syncthreads();

    float acc2 = ba2[tid];
    for (int k = 0; k < 256; ++k) acc2 = fmaf(an[k], Wa2[k * 256 + tid], acc2);

    float mx = block_max256(acc2, red);
    float e = __expf(acc2 - mx);
    float se = block_sum256(e, red);
    float contrib = v * e / se;
    float total = block_sum256(contrib, red);
    if (tid == 0) out[bs * 128 + o] = total;
}

// ---------------------------------------------------------------------------
// Launch
// ---------------------------------------------------------------------------
extern "C" void kernel_launch(void* const* d_in, const int* in_sizes, int n_in,
                              void* d_out, int out_size, void* d_ws, size_t ws_size,
                              hipStream_t stream) {
    const float* x      = (const float*)d_in[0];
    const float* ln0_g  = (const float*)d_in[1];
    const float* ln0_b  = (const float*)d_in[2];
    const float* W0     = (const float*)d_in[3];
    const float* b0     = (const float*)d_in[4];
    const float* rln_g  = (const float*)d_in[5];
    const float* rln_b  = (const float*)d_in[6];
    const float* rW     = (const float*)d_in[7];
    const float* rb     = (const float*)d_in[8];
    const float* lnf_g  = (const float*)d_in[9];
    const float* lnf_b  = (const float*)d_in[10];
    const float* Wf     = (const float*)d_in[11];
    const float* bf_    = (const float*)d_in[12];
    const float* ln1_g  = (const float*)d_in[13];
    const float* ln1_b  = (const float*)d_in[14];
    const float* Wa1    = (const float*)d_in[15];
    const float* ba1    = (const float*)d_in[16];
    const float* ln2_g  = (const float*)d_in[17];
    const float* ln2_b  = (const float*)d_in[18];
    const float* Wa2    = (const float*)d_in[19];
    const float* ba2    = (const float*)d_in[20];
    float* out = (float*)d_out;

    const int R = 64 * 256;   // 16384 rows
    float*  h  = (float*)d_ws;                          // R*1024 f32   (64 MB)
    ushort* Ap = (ushort*)(h + (size_t)R * 1024);       // R*1024*2 u16 (64 MB)
    float*  fc = (float*)(Ap + (size_t)R * 2048);       // R*128 f32    (8 MB)
    ushort* Wp = (ushort*)(fc + (size_t)R * 128);       // up to 4 MB

    // stem: h = relu(LN(x) @ W0 + b0)
    conv_w<<<dim3(16, 16), 64, 0, stream>>>(W0, Wp, 512, 1024);
    ln_pack<<<R, 256, 0, stream>>>(x, ln0_g, ln0_b, Ap, 512);
    gemm_mfma<0><<<dim3(128, 8), 256, 0, stream>>>(Ap, Wp, b0, h, R, 1024, 512);

    // residual blocks
    for (int i = 0; i < 8; ++i) {
        conv_w<<<dim3(16, 32), 64, 0, stream>>>(rW + (size_t)i * 1024 * 1024, Wp, 1024, 1024);
        ln_pack<<<R, 256, 0, stream>>>(h, rln_g + i * 1024, rln_b + i * 1024, Ap, 1024);
        gemm_mfma<1><<<dim3(128, 8), 256, 0, stream>>>(Ap, Wp, rb + i * 1024, h, R, 1024, 1024);
    }

    // head: fc = LN(h) @ Wf + bf
    conv_w<<<dim3(2, 32), 64, 0, stream>>>(Wf, Wp, 1024, 128);
    ln_pack<<<R, 256, 0, stream>>>(h, lnf_g, lnf_b, Ap, 1024);
    gemm_mfma<2><<<dim3(128, 1), 256, 0, stream>>>(Ap, Wp, bf_, fc, R, 128, 1024);

    // fused attention + weighted sum
    attn_fused<<<64 * 128, 256, 0, stream>>>(fc, ln1_g, ln1_b, Wa1, ba1,
                                             ln2_g, ln2_b, Wa2, ba2, out);
}

// Round 4
// 1356.110 us; speedup vs baseline: 2.8718x; 1.0634x over previous
//
#include <hip/hip_runtime.h>
#include <hip/hip_bf16.h>
#include <stdint.h>

#define EPSV 1e-5f

typedef __bf16 bf16x8 __attribute__((ext_vector_type(8)));
typedef float f32x4 __attribute__((ext_vector_type(4)));

// ---------------------------------------------------------------------------
// round-to-nearest bf16 split: f = hi + lo (both bf16), |f-(hi+lo)| ~ 2^-18 |f|
// ---------------------------------------------------------------------------
__device__ __forceinline__ void bf16split(float f, ushort& h, ushort& l) {
    union { float f; uint32_t u; } a; a.f = f;
    uint32_t r = a.u + 0x7FFFu + ((a.u >> 16) & 1u);
    h = (ushort)(r >> 16);
    union { uint32_t u; float f; } hf; hf.u = ((uint32_t)h) << 16;
    float lof = f - hf.f;
    union { float f; uint32_t u; } b; b.f = lof;
    uint32_t r2 = b.u + 0x7FFFu + ((b.u >> 16) & 1u);
    l = (ushort)(r2 >> 16);
}

__device__ __forceinline__ void gload_lds16(const void* g, void* l) {
    __builtin_amdgcn_global_load_lds(
        (const __attribute__((address_space(1))) uint32_t*)g,
        (__attribute__((address_space(3))) uint32_t*)l, 16, 0, 0);
}

// ---------------------------------------------------------------------------
// Block reduction helpers (256 threads = 4 waves of 64)
// ---------------------------------------------------------------------------
__device__ __forceinline__ float block_sum256(float v, float* red) {
#pragma unroll
    for (int off = 32; off; off >>= 1) v += __shfl_down(v, off);
    int lane = threadIdx.x & 63, w = threadIdx.x >> 6;
    __syncthreads();
    if (lane == 0) red[w] = v;
    __syncthreads();
    return red[0] + red[1] + red[2] + red[3];
}

// ---------------------------------------------------------------------------
// Row LayerNorm -> packed hi/lo bf16 output.
// Packed layout: Ap[row][kt][half][km]  (ushort), kt = k/32, km = k%32,
// half 0 = hi, 1 = lo. Row stride = D*2 ushorts = D*4 bytes.
// ---------------------------------------------------------------------------
__global__ __launch_bounds__(256)
void ln_pack(const float* __restrict__ X, const float* __restrict__ g,
             const float* __restrict__ b, ushort* __restrict__ Ap, int D) {
    __shared__ float red[4];
    int row = blockIdx.x;
    const float* x = X + (size_t)row * D;
    ushort* ap = Ap + (size_t)row * (D * 2);
    int tid = threadIdx.x;
    int nvec = D >> 2;

    float s = 0.f, sq = 0.f;
    for (int i = tid; i < nvec; i += 256) {
        float4 v = ((const float4*)x)[i];
        s += v.x + v.y + v.z + v.w;
        sq += v.x * v.x + v.y * v.y + v.z * v.z + v.w * v.w;
    }
    float ts = block_sum256(s, red);
    float tq = block_sum256(sq, red);
    float invD = 1.f / (float)D;
    float mu = ts * invD;
    float var = tq * invD - mu * mu;
    float rstd = rsqrtf(var + EPSV);

    for (int i = tid; i < nvec; i += 256) {
        float4 v = ((const float4*)x)[i];
        float4 gv = ((const float4*)g)[i];
        float4 bv = ((const float4*)b)[i];
        float o[4];
        o[0] = (v.x - mu) * rstd * gv.x + bv.x;
        o[1] = (v.y - mu) * rstd * gv.y + bv.y;
        o[2] = (v.z - mu) * rstd * gv.z + bv.z;
        o[3] = (v.w - mu) * rstd * gv.w + bv.w;
        ushort hi[4], lo[4];
#pragma unroll
        for (int j = 0; j < 4; ++j) bf16split(o[j], hi[j], lo[j]);
        int kt = i >> 3;           // (4i)/32
        int km = (i & 7) << 2;     // (4i)%32
        ushort* dst = ap + kt * 64 + km;
        *(ushort4*)dst = *(ushort4*)hi;
        *(ushort4*)(dst + 32) = *(ushort4*)lo;
    }
}

// ---------------------------------------------------------------------------
// Weight convert+transpose: W[K][N] fp32 -> Wp[n][kt][half][km] packed bf16.
// grid = (ceil(N/64), K/32), block = 64.
// ---------------------------------------------------------------------------
__global__ __launch_bounds__(64)
void conv_w(const float* __restrict__ W, ushort* __restrict__ Wp, int K, int N) {
    int n = blockIdx.x * 64 + threadIdx.x;
    int kt = blockIdx.y;
    if (n >= N) return;
    ushort hi[32], lo[32];
#pragma unroll
    for (int j = 0; j < 32; ++j) {
        float f = W[(size_t)(kt * 32 + j) * N + n];
        bf16split(f, hi[j], lo[j]);
    }
    ushort* dst = Wp + (size_t)n * (K * 2) + kt * 64;
    uint4* d = (uint4*)dst;
    const uint4* ph = (const uint4*)hi;
    const uint4* pl = (const uint4*)lo;
    d[0] = ph[0]; d[1] = ph[1]; d[2] = ph[2]; d[3] = ph[3];
    d[4] = pl[0]; d[5] = pl[1]; d[6] = pl[2]; d[7] = pl[3];
}

// ---------------------------------------------------------------------------
// Split-bf16 MFMA GEMM. C = A@B (+bias, relu, residual per MODE), fp32 out.
// Same core as round 2 (verified passing); adds T1 XCD-chunked block swizzle.
// ---------------------------------------------------------------------------
template <int MODE>
__global__ __launch_bounds__(256)
void gemm_mfma(const ushort* __restrict__ Ap, const ushort* __restrict__ Bp,
               const float* __restrict__ bias, float* __restrict__ C,
               int M, int N, int K) {
    __shared__ ushort Ash[128 * 64];   // 128 rows x 128B
    __shared__ ushort Bsh[128 * 64];

    const int tid = threadIdx.x;
    const int lane = tid & 63;
    const int wv = tid >> 6;
    const int wr = wv >> 1, wc = wv & 1;

    // T1: XCD-chunked swizzle (nwg % 8 == 0 for all launches here).
    int lid = blockIdx.y * gridDim.x + blockIdx.x;
    int nwg = gridDim.x * gridDim.y;
    int chunk = nwg >> 3;
    int swz = (lid & 7) * chunk + (lid >> 3);
    int nIdx = swz % gridDim.y;
    int mIdx = swz / gridDim.y;
    const int m0 = mIdx * 128, n0 = nIdx * 128;

    const int ktc = K >> 5;
    const size_t rowB = (size_t)K * 4;   // packed row bytes

    int srow[4], sq[4];
#pragma unroll
    for (int i = 0; i < 4; ++i) {
        int s = i * 256 + tid;
        srow[i] = s >> 3;
        sq[i] = (s & 7) ^ (srow[i] & 7);
    }

    f32x4 acc[4][4] = {};

    for (int kt = 0; kt < ktc; ++kt) {
        __syncthreads();
#pragma unroll
        for (int i = 0; i < 4; ++i) {
            const char* sA = (const char*)Ap + (size_t)(m0 + srow[i]) * rowB + kt * 128 + sq[i] * 16;
            const char* sB = (const char*)Bp + (size_t)(n0 + srow[i]) * rowB + kt * 128 + sq[i] * 16;
            gload_lds16(sA, (char*)Ash + (i * 256 + tid) * 16);
            gload_lds16(sB, (char*)Bsh + (i * 256 + tid) * 16);
        }
        __syncthreads();

        bf16x8 ah[4], al[4], bh[4], bl[4];
        const int g = lane >> 4;
        const int rr = lane & 15;
#pragma unroll
        for (int t = 0; t < 4; ++t) {
            int rA = wr * 64 + t * 16 + rr;
            const char* baseA = (const char*)Ash + rA * 128;
            ah[t] = *(const bf16x8*)(baseA + ((g ^ (rA & 7)) * 16));
            al[t] = *(const bf16x8*)(baseA + (((g + 4) ^ (rA & 7)) * 16));
            int rBr = wc * 64 + t * 16 + rr;
            const char* baseB = (const char*)Bsh + rBr * 128;
            bh[t] = *(const bf16x8*)(baseB + ((g ^ (rBr & 7)) * 16));
            bl[t] = *(const bf16x8*)(baseB + (((g + 4) ^ (rBr & 7)) * 16));
        }
#pragma unroll
        for (int mi = 0; mi < 4; ++mi)
#pragma unroll
            for (int ni = 0; ni < 4; ++ni) {
                acc[mi][ni] = __builtin_amdgcn_mfma_f32_16x16x32_bf16(ah[mi], bh[ni], acc[mi][ni], 0, 0, 0);
                acc[mi][ni] = __builtin_amdgcn_mfma_f32_16x16x32_bf16(al[mi], bh[ni], acc[mi][ni], 0, 0, 0);
                acc[mi][ni] = __builtin_amdgcn_mfma_f32_16x16x32_bf16(ah[mi], bl[ni], acc[mi][ni], 0, 0, 0);
            }
    }

#pragma unroll
    for (int mi = 0; mi < 4; ++mi) {
        int r = m0 + wr * 64 + mi * 16 + (lane >> 4) * 4;
#pragma unroll
        for (int ni = 0; ni < 4; ++ni) {
            int c = n0 + wc * 64 + ni * 16 + (lane & 15);
            float bv = bias[c];
#pragma unroll
            for (int j = 0; j < 4; ++j) {
                float v = acc[mi][ni][j] + bv;
                float* cp = &C[(size_t)(r + j) * N + c];
                if (MODE == 0) *cp = fmaxf(v, 0.f);
                else if (MODE == 1) *cp = *cp + fmaxf(v, 0.f);
                else *cp = v;
            }
        }
    }
}

// ---------------------------------------------------------------------------
// 16-wide simultaneous block reduction: v[16] per thread -> out[16] (shared).
// ---------------------------------------------------------------------------
template <bool MAXOP>
__device__ __forceinline__ void red16(const float* v, float* out, float (*scr)[4]) {
    int lane = threadIdx.x & 63, wv = threadIdx.x >> 6, tid = threadIdx.x;
#pragma unroll
    for (int oo = 0; oo < 16; ++oo) {
        float r = v[oo];
#pragma unroll
        for (int m = 1; m < 64; m <<= 1) {
            float t = __shfl_xor(r, m);
            r = MAXOP ? fmaxf(r, t) : r + t;
        }
        if (lane == 0) scr[oo][wv] = r;
    }
    __syncthreads();
    if (tid < 16) {
        float a = scr[tid][0], b = scr[tid][1], c = scr[tid][2], d = scr[tid][3];
        out[tid] = MAXOP ? fmaxf(fmaxf(a, b), fmaxf(c, d)) : (a + b + c + d);
    }
    __syncthreads();
}

__device__ __forceinline__ void fma16(float* acc, const float* buf, float w) {
#pragma unroll
    for (int oo = 0; oo < 16; ++oo) acc[oo] = fmaf(buf[oo], w, acc[oo]);
}

// ---------------------------------------------------------------------------
// Attention over time, 16 outputs per block. grid = 64 bs * 8 ogroups.
// ---------------------------------------------------------------------------
__global__ __launch_bounds__(256)
void attn_g16(const float* __restrict__ fc,
              const float* __restrict__ g1, const float* __restrict__ b1,
              const float* __restrict__ Wa1, const float* __restrict__ ba1,
              const float* __restrict__ g2, const float* __restrict__ b2,
              const float* __restrict__ Wa2, const float* __restrict__ ba2,
              float* __restrict__ out) {
    __shared__ float buf[257][16];
    __shared__ float scr[16][4];
    __shared__ float sS[16], sQ[16], sO[16];

    int bs = blockIdx.x >> 3;
    int o0 = (blockIdx.x & 7) * 16;
    int tid = threadIdx.x;

    float vv[16], tmp[16];
    const float4* fp = (const float4*)(fc + (size_t)(bs * 256 + tid) * 128 + o0);
#pragma unroll
    for (int q = 0; q < 4; ++q) {
        float4 t = fp[q];
        vv[4 * q] = t.x; vv[4 * q + 1] = t.y; vv[4 * q + 2] = t.z; vv[4 * q + 3] = t.w;
    }

#pragma unroll
    for (int oo = 0; oo < 16; ++oo) tmp[oo] = vv[oo] * vv[oo];
    red16<false>(vv, sS, scr);    // per-oo sum over time
    red16<false>(tmp, sQ, scr);   // per-oo sumsq over time

    // LN over 257-vector [v_0..255, mean]
    float gl = g1[tid], bl = b1[tid];
#pragma unroll
    for (int oo = 0; oo < 16; ++oo) {
        float s = sS[oo], q = sQ[oo];
        float mean = s * (1.f / 256.f);
        float mu = (s + mean) * (1.f / 257.f);
        float var = (q + mean * mean) * (1.f / 257.f) - mu * mu;
        float rstd = rsqrtf(var + EPSV);
        buf[tid][oo] = (vv[oo] - mu) * rstd * gl + bl;
    }
    if (tid < 16) {
        int oo = tid;
        float s = sS[oo], q = sQ[oo];
        float mean = s * (1.f / 256.f);
        float mu = (s + mean) * (1.f / 257.f);
        float var = (q + mean * mean) * (1.f / 257.f) - mu * mu;
        float rstd = rsqrtf(var + EPSV);
        buf[256][oo] = (mean - mu) * rstd * g1[256] + b1[256];
    }
    __syncthreads();

    // GEMV1: a[oo][j=tid] = relu(sum_k buf[k][oo]*Wa1[k][j] + ba1[j])
    float a_[16] = {};
    const float* w1 = Wa1 + tid;
#pragma unroll 4
    for (int k = 0; k < 257; ++k) fma16(a_, &buf[k][0], w1[(size_t)k * 256]);
    float bb = ba1[tid];
#pragma unroll
    for (int oo = 0; oo < 16; ++oo) a_[oo] = fmaxf(a_[oo] + bb, 0.f);

    // LN over a (256 j's)
#pragma unroll
    for (int oo = 0; oo < 16; ++oo) tmp[oo] = a_[oo] * a_[oo];
    red16<false>(a_, sS, scr);
    red16<false>(tmp, sQ, scr);

    float g2l = g2[tid], b2l = b2[tid];
#pragma unroll
    for (int oo = 0; oo < 16; ++oo) {
        float mu2 = sS[oo] * (1.f / 256.f);
        float rstd2 = rsqrtf(sQ[oo] * (1.f / 256.f) - mu2 * mu2 + EPSV);
        buf[tid][oo] = (a_[oo] - mu2) * rstd2 * g2l + b2l;
    }
    __syncthreads();

    // GEMV2: w[oo][l=tid] = sum_j buf[j][oo]*Wa2[j*256 + l] + ba2[l]
    float w_[16] = {};
    const float* w2 = Wa2 + tid;
#pragma unroll 4
    for (int j = 0; j < 256; ++j) fma16(w_, &buf[j][0], w2[(size_t)j * 256]);
    float bb2 = ba2[tid];
#pragma unroll
    for (int oo = 0; oo < 16; ++oo) w_[oo] += bb2;

    // softmax over l per oo, then weighted sum
    red16<true>(w_, sO, scr);
    float e_[16];
#pragma unroll
    for (int oo = 0; oo < 16; ++oo) e_[oo] = __expf(w_[oo] - sO[oo]);
    red16<false>(e_, sS, scr);
#pragma unroll
    for (int oo = 0; oo < 16; ++oo) tmp[oo] = vv[oo] * e_[oo] / sS[oo];
    red16<false>(tmp, sQ, scr);
    if (tid < 16) out[bs * 128 + o0 + tid] = sQ[tid];
}

// ---------------------------------------------------------------------------
// Launch
// ---------------------------------------------------------------------------
extern "C" void kernel_launch(void* const* d_in, const int* in_sizes, int n_in,
                              void* d_out, int out_size, void* d_ws, size_t ws_size,
                              hipStream_t stream) {
    const float* x      = (const float*)d_in[0];
    const float* ln0_g  = (const float*)d_in[1];
    const float* ln0_b  = (const float*)d_in[2];
    const float* W0     = (const float*)d_in[3];
    const float* b0     = (const float*)d_in[4];
    const float* rln_g  = (const float*)d_in[5];
    const float* rln_b  = (const float*)d_in[6];
    const float* rW     = (const float*)d_in[7];
    const float* rb     = (const float*)d_in[8];
    const float* lnf_g  = (const float*)d_in[9];
    const float* lnf_b  = (const float*)d_in[10];
    const float* Wf     = (const float*)d_in[11];
    const float* bf_    = (const float*)d_in[12];
    const float* ln1_g  = (const float*)d_in[13];
    const float* ln1_b  = (const float*)d_in[14];
    const float* Wa1    = (const float*)d_in[15];
    const float* ba1    = (const float*)d_in[16];
    const float* ln2_g  = (const float*)d_in[17];
    const float* ln2_b  = (const float*)d_in[18];
    const float* Wa2    = (const float*)d_in[19];
    const float* ba2    = (const float*)d_in[20];
    float* out = (float*)d_out;

    const int R = 64 * 256;   // 16384 rows
    float*  h  = (float*)d_ws;                          // R*1024 f32   (64 MB)
    ushort* Ap = (ushort*)(h + (size_t)R * 1024);       // R*1024*2 u16 (64 MB)
    float*  fc = (float*)(Ap + (size_t)R * 2048);       // R*128 f32    (8 MB)
    ushort* Wp = (ushort*)(fc + (size_t)R * 128);       // up to 4 MB

    // stem: h = relu(LN(x) @ W0 + b0)
    conv_w<<<dim3(16, 16), 64, 0, stream>>>(W0, Wp, 512, 1024);
    ln_pack<<<R, 256, 0, stream>>>(x, ln0_g, ln0_b, Ap, 512);
    gemm_mfma<0><<<dim3(128, 8), 256, 0, stream>>>(Ap, Wp, b0, h, R, 1024, 512);

    // residual blocks
    for (int i = 0; i < 8; ++i) {
        conv_w<<<dim3(16, 32), 64, 0, stream>>>(rW + (size_t)i * 1024 * 1024, Wp, 1024, 1024);
        ln_pack<<<R, 256, 0, stream>>>(h, rln_g + i * 1024, rln_b + i * 1024, Ap, 1024);
        gemm_mfma<1><<<dim3(128, 8), 256, 0, stream>>>(Ap, Wp, rb + i * 1024, h, R, 1024, 1024);
    }

    // head: fc = LN(h) @ Wf + bf
    conv_w<<<dim3(2, 32), 64, 0, stream>>>(Wf, Wp, 1024, 128);
    ln_pack<<<R, 256, 0, stream>>>(h, lnf_g, lnf_b, Ap, 1024);
    gemm_mfma<2><<<dim3(128, 1), 256, 0, stream>>>(Ap, Wp, bf_, fc, R, 128, 1024);

    // fused attention + weighted sum (16 outputs per block)
    attn_g16<<<64 * 8, 256, 0, stream>>>(fc, ln1_g, ln1_b, Wa1, ba1,
                                         ln2_g, ln2_b, Wa2, ba2, out);
}

// Round 5
// 1247.786 us; speedup vs baseline: 3.1211x; 1.0868x over previous
//
#include <hip/hip_runtime.h>
#include <hip/hip_bf16.h>
#include <stdint.h>

#define EPSV 1e-5f

typedef __bf16 bf16x8 __attribute__((ext_vector_type(8)));
typedef float f32x4 __attribute__((ext_vector_type(4)));

// ---------------------------------------------------------------------------
// round-to-nearest bf16 split: f = hi + lo (both bf16), |f-(hi+lo)| ~ 2^-18 |f|
// ---------------------------------------------------------------------------
__device__ __forceinline__ void bf16split(float f, ushort& h, ushort& l) {
    union { float f; uint32_t u; } a; a.f = f;
    uint32_t r = a.u + 0x7FFFu + ((a.u >> 16) & 1u);
    h = (ushort)(r >> 16);
    union { uint32_t u; float f; } hf; hf.u = ((uint32_t)h) << 16;
    float lof = f - hf.f;
    union { float f; uint32_t u; } b; b.f = lof;
    uint32_t r2 = b.u + 0x7FFFu + ((b.u >> 16) & 1u);
    l = (ushort)(r2 >> 16);
}

__device__ __forceinline__ void gload_lds16(const void* g, void* l) {
    __builtin_amdgcn_global_load_lds(
        (const __attribute__((address_space(1))) uint32_t*)g,
        (__attribute__((address_space(3))) uint32_t*)l, 16, 0, 0);
}

// ---------------------------------------------------------------------------
// Block reduction helpers (256 threads = 4 waves of 64)
// ---------------------------------------------------------------------------
__device__ __forceinline__ float block_sum256(float v, float* red) {
#pragma unroll
    for (int off = 32; off; off >>= 1) v += __shfl_down(v, off);
    int lane = threadIdx.x & 63, w = threadIdx.x >> 6;
    __syncthreads();
    if (lane == 0) red[w] = v;
    __syncthreads();
    return red[0] + red[1] + red[2] + red[3];
}

// ---------------------------------------------------------------------------
// Row LayerNorm -> packed hi/lo bf16 output.
// Packed layout: Ap[row][kt][half][km]  (ushort), kt = k/32, km = k%32,
// half 0 = hi, 1 = lo. Row stride = D*2 ushorts = D*4 bytes.
// ---------------------------------------------------------------------------
__global__ __launch_bounds__(256)
void ln_pack(const float* __restrict__ X, const float* __restrict__ g,
             const float* __restrict__ b, ushort* __restrict__ Ap, int D) {
    __shared__ float red[4];
    int row = blockIdx.x;
    const float* x = X + (size_t)row * D;
    ushort* ap = Ap + (size_t)row * (D * 2);
    int tid = threadIdx.x;
    int nvec = D >> 2;

    float s = 0.f, sq = 0.f;
    for (int i = tid; i < nvec; i += 256) {
        float4 v = ((const float4*)x)[i];
        s += v.x + v.y + v.z + v.w;
        sq += v.x * v.x + v.y * v.y + v.z * v.z + v.w * v.w;
    }
    float ts = block_sum256(s, red);
    float tq = block_sum256(sq, red);
    float invD = 1.f / (float)D;
    float mu = ts * invD;
    float var = tq * invD - mu * mu;
    float rstd = rsqrtf(var + EPSV);

    for (int i = tid; i < nvec; i += 256) {
        float4 v = ((const float4*)x)[i];
        float4 gv = ((const float4*)g)[i];
        float4 bv = ((const float4*)b)[i];
        float o[4];
        o[0] = (v.x - mu) * rstd * gv.x + bv.x;
        o[1] = (v.y - mu) * rstd * gv.y + bv.y;
        o[2] = (v.z - mu) * rstd * gv.z + bv.z;
        o[3] = (v.w - mu) * rstd * gv.w + bv.w;
        ushort hi[4], lo[4];
#pragma unroll
        for (int j = 0; j < 4; ++j) bf16split(o[j], hi[j], lo[j]);
        int kt = i >> 3;           // (4i)/32
        int km = (i & 7) << 2;     // (4i)%32
        ushort* dst = ap + kt * 64 + km;
        *(ushort4*)dst = *(ushort4*)hi;
        *(ushort4*)(dst + 32) = *(ushort4*)lo;
    }
}

// ---------------------------------------------------------------------------
// Weight convert+transpose: W[K][N] fp32 -> Wp[n][kt][half][km] packed bf16.
// grid = (ceil(N/64), K/32), block = 64.
// ---------------------------------------------------------------------------
__global__ __launch_bounds__(64)
void conv_w(const float* __restrict__ W, ushort* __restrict__ Wp, int K, int N) {
    int n = blockIdx.x * 64 + threadIdx.x;
    int kt = blockIdx.y;
    if (n >= N) return;
    ushort hi[32], lo[32];
#pragma unroll
    for (int j = 0; j < 32; ++j) {
        float f = W[(size_t)(kt * 32 + j) * N + n];
        bf16split(f, hi[j], lo[j]);
    }
    ushort* dst = Wp + (size_t)n * (K * 2) + kt * 64;
    uint4* d = (uint4*)dst;
    const uint4* ph = (const uint4*)hi;
    const uint4* pl = (const uint4*)lo;
    d[0] = ph[0]; d[1] = ph[1]; d[2] = ph[2]; d[3] = ph[3];
    d[4] = pl[0]; d[5] = pl[1]; d[6] = pl[2]; d[7] = pl[3];
}

// ---------------------------------------------------------------------------
// 256x256-tile split-bf16 MFMA GEMM, 8 waves, double-buffered LDS,
// issue-early staging, ONE barrier per K-tile (BK=32 packed chunk).
// Waves: 2(M) x 4(N); per-wave output 128x64; per k-tile 3 product phases
// (hh, lh, hl) reading each LDS fragment exactly once.
// MODE 0: C = relu(AB+bias); 1: C += relu(AB+bias); 2: C = AB+bias.
// Requires M%256==0, N%256==0, K%32==0, grid (M/256, N/256), nwg%8==0.
// ---------------------------------------------------------------------------
template <int MODE>
__global__ __launch_bounds__(512, 2)
void gemm_mfma256(const ushort* __restrict__ Ap, const ushort* __restrict__ Bp,
                  const float* __restrict__ bias, float* __restrict__ C,
                  int M, int N, int K) {
    __shared__ ushort Abuf[2][256 * 64];   // 2 x 32 KB
    __shared__ ushort Bbuf[2][256 * 64];   // 2 x 32 KB

    const int tid = threadIdx.x;
    const int lane = tid & 63;
    const int wv = tid >> 6;       // 0..7
    const int wr = wv >> 2;        // 0..1  (M)
    const int wc = wv & 3;         // 0..3  (N)

    // T1 XCD-chunked swizzle
    int lid = blockIdx.y * gridDim.x + blockIdx.x;
    int nwg = gridDim.x * gridDim.y;
    int chunk = nwg >> 3;
    int swz = (lid & 7) * chunk + (lid >> 3);
    int nIdx = swz % gridDim.y;
    int mIdx = swz / gridDim.y;
    const int m0 = mIdx * 256, n0 = nIdx * 256;

    const int nt = K >> 5;
    const size_t rowB = (size_t)K * 4;   // packed row bytes

    // staging slots: 4 rounds for A + 4 for B; slot s = rnd*512 + tid
    // LDS dest linear (slot*16); global source chunk pre-swizzled by row&7.
    int srow[4], sq[4];
#pragma unroll
    for (int i = 0; i < 4; ++i) {
        int s = i * 512 + tid;
        srow[i] = s >> 3;                  // 0..255
        sq[i] = (s & 7) ^ (srow[i] & 7);
    }

    f32x4 acc[8][4] = {};

    // prologue: stage tile 0 into buffer 0
#pragma unroll
    for (int i = 0; i < 4; ++i) {
        const char* sA = (const char*)Ap + (size_t)(m0 + srow[i]) * rowB + sq[i] * 16;
        const char* sB = (const char*)Bp + (size_t)(n0 + srow[i]) * rowB + sq[i] * 16;
        gload_lds16(sA, (char*)Abuf[0] + (i * 512 + tid) * 16);
        gload_lds16(sB, (char*)Bbuf[0] + (i * 512 + tid) * 16);
    }
    __syncthreads();   // compiler drains vmcnt before s_barrier -> tile 0 ready

    int p = 0;
    for (int kt = 0; kt < nt; ++kt) {
        // issue next tile's loads FIRST -- they land under this tile's MFMA
        if (kt + 1 < nt) {
            const size_t koff = (size_t)(kt + 1) * 128;
#pragma unroll
            for (int i = 0; i < 4; ++i) {
                const char* sA = (const char*)Ap + (size_t)(m0 + srow[i]) * rowB + koff + sq[i] * 16;
                const char* sB = (const char*)Bp + (size_t)(n0 + srow[i]) * rowB + koff + sq[i] * 16;
                gload_lds16(sA, (char*)Abuf[p ^ 1] + (i * 512 + tid) * 16);
                gload_lds16(sB, (char*)Bbuf[p ^ 1] + (i * 512 + tid) * 16);
            }
        }

        const char* Ab = (const char*)Abuf[p];
        const char* Bb = (const char*)Bbuf[p];
        const int g = lane >> 4;
        const int rr = lane & 15;

        // P1: hi(A) x hi(B)
        bf16x8 ah[8], bh[4];
#pragma unroll
        for (int m = 0; m < 8; ++m) {
            int rA = wr * 128 + m * 16 + rr;
            ah[m] = *(const bf16x8*)(Ab + rA * 128 + ((g ^ (rA & 7)) * 16));
        }
#pragma unroll
        for (int n = 0; n < 4; ++n) {
            int rB = wc * 64 + n * 16 + rr;
            bh[n] = *(const bf16x8*)(Bb + rB * 128 + ((g ^ (rB & 7)) * 16));
        }
#pragma unroll
        for (int m = 0; m < 8; ++m)
#pragma unroll
            for (int n = 0; n < 4; ++n)
                acc[m][n] = __builtin_amdgcn_mfma_f32_16x16x32_bf16(ah[m], bh[n], acc[m][n], 0, 0, 0);

        // P2: lo(A) x hi(B)   (al scoped -> dies after use)
        {
            bf16x8 al[8];
#pragma unroll
            for (int m = 0; m < 8; ++m) {
                int rA = wr * 128 + m * 16 + rr;
                al[m] = *(const bf16x8*)(Ab + rA * 128 + (((g + 4) ^ (rA & 7)) * 16));
            }
#pragma unroll
            for (int m = 0; m < 8; ++m)
#pragma unroll
                for (int n = 0; n < 4; ++n)
                    acc[m][n] = __builtin_amdgcn_mfma_f32_16x16x32_bf16(al[m], bh[n], acc[m][n], 0, 0, 0);
        }
        // P3: hi(A) x lo(B)
        {
            bf16x8 bl[4];
#pragma unroll
            for (int n = 0; n < 4; ++n) {
                int rB = wc * 64 + n * 16 + rr;
                bl[n] = *(const bf16x8*)(Bb + rB * 128 + (((g + 4) ^ (rB & 7)) * 16));
            }
#pragma unroll
            for (int m = 0; m < 8; ++m)
#pragma unroll
                for (int n = 0; n < 4; ++n)
                    acc[m][n] = __builtin_amdgcn_mfma_f32_16x16x32_bf16(ah[m], bl[n], acc[m][n], 0, 0, 0);
        }

        __syncthreads();   // ds_reads of buf[p] done + next tile's loads landed
        p ^= 1;
    }

    // epilogue: C/D layout col = lane&15, row = (lane>>4)*4 + j  [m89/m91]
#pragma unroll
    for (int m = 0; m < 8; ++m) {
        int r = m0 + wr * 128 + m * 16 + (lane >> 4) * 4;
#pragma unroll
        for (int n = 0; n < 4; ++n) {
            int c = n0 + wc * 64 + n * 16 + (lane & 15);
            float bv = bias[c];
#pragma unroll
            for (int j = 0; j < 4; ++j) {
                float v = acc[m][n][j] + bv;
                float* cp = &C[(size_t)(r + j) * N + c];
                if (MODE == 0) *cp = fmaxf(v, 0.f);
                else if (MODE == 1) *cp = *cp + fmaxf(v, 0.f);
                else *cp = v;
            }
        }
    }
}

// ---------------------------------------------------------------------------
// 128x128-tile split-bf16 MFMA GEMM (proven, round-2/4 core) -- head (N=128).
// ---------------------------------------------------------------------------
template <int MODE>
__global__ __launch_bounds__(256)
void gemm_mfma(const ushort* __restrict__ Ap, const ushort* __restrict__ Bp,
               const float* __restrict__ bias, float* __restrict__ C,
               int M, int N, int K) {
    __shared__ ushort Ash[128 * 64];
    __shared__ ushort Bsh[128 * 64];

    const int tid = threadIdx.x;
    const int lane = tid & 63;
    const int wv = tid >> 6;
    const int wr = wv >> 1, wc = wv & 1;

    int lid = blockIdx.y * gridDim.x + blockIdx.x;
    int nwg = gridDim.x * gridDim.y;
    int chunk = nwg >> 3;
    int swz = (lid & 7) * chunk + (lid >> 3);
    int nIdx = swz % gridDim.y;
    int mIdx = swz / gridDim.y;
    const int m0 = mIdx * 128, n0 = nIdx * 128;

    const int ktc = K >> 5;
    const size_t rowB = (size_t)K * 4;

    int srow[4], sq[4];
#pragma unroll
    for (int i = 0; i < 4; ++i) {
        int s = i * 256 + tid;
        srow[i] = s >> 3;
        sq[i] = (s & 7) ^ (srow[i] & 7);
    }

    f32x4 acc[4][4] = {};

    for (int kt = 0; kt < ktc; ++kt) {
        __syncthreads();
#pragma unroll
        for (int i = 0; i < 4; ++i) {
            const char* sA = (const char*)Ap + (size_t)(m0 + srow[i]) * rowB + kt * 128 + sq[i] * 16;
            const char* sB = (const char*)Bp + (size_t)(n0 + srow[i]) * rowB + kt * 128 + sq[i] * 16;
            gload_lds16(sA, (char*)Ash + (i * 256 + tid) * 16);
            gload_lds16(sB, (char*)Bsh + (i * 256 + tid) * 16);
        }
        __syncthreads();

        bf16x8 ah[4], al[4], bh[4], bl[4];
        const int g = lane >> 4;
        const int rr = lane & 15;
#pragma unroll
        for (int t = 0; t < 4; ++t) {
            int rA = wr * 64 + t * 16 + rr;
            const char* baseA = (const char*)Ash + rA * 128;
            ah[t] = *(const bf16x8*)(baseA + ((g ^ (rA & 7)) * 16));
            al[t] = *(const bf16x8*)(baseA + (((g + 4) ^ (rA & 7)) * 16));
            int rBr = wc * 64 + t * 16 + rr;
            const char* baseB = (const char*)Bsh + rBr * 128;
            bh[t] = *(const bf16x8*)(baseB + ((g ^ (rBr & 7)) * 16));
            bl[t] = *(const bf16x8*)(baseB + (((g + 4) ^ (rBr & 7)) * 16));
        }
#pragma unroll
        for (int mi = 0; mi < 4; ++mi)
#pragma unroll
            for (int ni = 0; ni < 4; ++ni) {
                acc[mi][ni] = __builtin_amdgcn_mfma_f32_16x16x32_bf16(ah[mi], bh[ni], acc[mi][ni], 0, 0, 0);
                acc[mi][ni] = __builtin_amdgcn_mfma_f32_16x16x32_bf16(al[mi], bh[ni], acc[mi][ni], 0, 0, 0);
                acc[mi][ni] = __builtin_amdgcn_mfma_f32_16x16x32_bf16(ah[mi], bl[ni], acc[mi][ni], 0, 0, 0);
            }
    }

#pragma unroll
    for (int mi = 0; mi < 4; ++mi) {
        int r = m0 + wr * 64 + mi * 16 + (lane >> 4) * 4;
#pragma unroll
        for (int ni = 0; ni < 4; ++ni) {
            int c = n0 + wc * 64 + ni * 16 + (lane & 15);
            float bv = bias[c];
#pragma unroll
            for (int j = 0; j < 4; ++j) {
                float v = acc[mi][ni][j] + bv;
                float* cp = &C[(size_t)(r + j) * N + c];
                if (MODE == 0) *cp = fmaxf(v, 0.f);
                else if (MODE == 1) *cp = *cp + fmaxf(v, 0.f);
                else *cp = v;
            }
        }
    }
}

// ---------------------------------------------------------------------------
// 16-wide simultaneous block reduction: v[16] per thread -> out[16] (shared).
// ---------------------------------------------------------------------------
template <bool MAXOP>
__device__ __forceinline__ void red16(const float* v, float* out, float (*scr)[4]) {
    int lane = threadIdx.x & 63, wv = threadIdx.x >> 6, tid = threadIdx.x;
#pragma unroll
    for (int oo = 0; oo < 16; ++oo) {
        float r = v[oo];
#pragma unroll
        for (int m = 1; m < 64; m <<= 1) {
            float t = __shfl_xor(r, m);
            r = MAXOP ? fmaxf(r, t) : r + t;
        }
        if (lane == 0) scr[oo][wv] = r;
    }
    __syncthreads();
    if (tid < 16) {
        float a = scr[tid][0], b = scr[tid][1], c = scr[tid][2], d = scr[tid][3];
        out[tid] = MAXOP ? fmaxf(fmaxf(a, b), fmaxf(c, d)) : (a + b + c + d);
    }
    __syncthreads();
}

__device__ __forceinline__ void fma16(float* acc, const float* buf, float w) {
#pragma unroll
    for (int oo = 0; oo < 16; ++oo) acc[oo] = fmaf(buf[oo], w, acc[oo]);
}

// ---------------------------------------------------------------------------
// Attention over time, 16 outputs per block. grid = 64 bs * 8 ogroups.
// ---------------------------------------------------------------------------
__global__ __launch_bounds__(256)
void attn_g16(const float* __restrict__ fc,
              const float* __restrict__ g1, const float* __restrict__ b1,
              const float* __restrict__ Wa1, const float* __restrict__ ba1,
              const float* __restrict__ g2, const float* __restrict__ b2,
              const float* __restrict__ Wa2, const float* __restrict__ ba2,
              float* __restrict__ out) {
    __shared__ float buf[257][16];
    __shared__ float scr[16][4];
    __shared__ float sS[16], sQ[16], sO[16];

    int bs = blockIdx.x >> 3;
    int o0 = (blockIdx.x & 7) * 16;
    int tid = threadIdx.x;

    float vv[16], tmp[16];
    const float4* fp = (const float4*)(fc + (size_t)(bs * 256 + tid) * 128 + o0);
#pragma unroll
    for (int q = 0; q < 4; ++q) {
        float4 t = fp[q];
        vv[4 * q] = t.x; vv[4 * q + 1] = t.y; vv[4 * q + 2] = t.z; vv[4 * q + 3] = t.w;
    }

#pragma unroll
    for (int oo = 0; oo < 16; ++oo) tmp[oo] = vv[oo] * vv[oo];
    red16<false>(vv, sS, scr);
    red16<false>(tmp, sQ, scr);

    float gl = g1[tid], bl = b1[tid];
#pragma unroll
    for (int oo = 0; oo < 16; ++oo) {
        float s = sS[oo], q = sQ[oo];
        float mean = s * (1.f / 256.f);
        float mu = (s + mean) * (1.f / 257.f);
        float var = (q + mean * mean) * (1.f / 257.f) - mu * mu;
        float rstd = rsqrtf(var + EPSV);
        buf[tid][oo] = (vv[oo] - mu) * rstd * gl + bl;
    }
    if (tid < 16) {
        int oo = tid;
        float s = sS[oo], q = sQ[oo];
        float mean = s * (1.f / 256.f);
        float mu = (s + mean) * (1.f / 257.f);
        float var = (q + mean * mean) * (1.f / 257.f) - mu * mu;
        float rstd = rsqrtf(var + EPSV);
        buf[256][oo] = (mean - mu) * rstd * g1[256] + b1[256];
    }
    __syncthreads();

    float a_[16] = {};
    const float* w1 = Wa1 + tid;
#pragma unroll 4
    for (int k = 0; k < 257; ++k) fma16(a_, &buf[k][0], w1[(size_t)k * 256]);
    float bb = ba1[tid];
#pragma unroll
    for (int oo = 0; oo < 16; ++oo) a_[oo] = fmaxf(a_[oo] + bb, 0.f);

#pragma unroll
    for (int oo = 0; oo < 16; ++oo) tmp[oo] = a_[oo] * a_[oo];
    red16<false>(a_, sS, scr);
    red16<false>(tmp, sQ, scr);

    float g2l = g2[tid], b2l = b2[tid];
#pragma unroll
    for (int oo = 0; oo < 16; ++oo) {
        float mu2 = sS[oo] * (1.f / 256.f);
        float rstd2 = rsqrtf(sQ[oo] * (1.f / 256.f) - mu2 * mu2 + EPSV);
        buf[tid][oo] = (a_[oo] - mu2) * rstd2 * g2l + b2l;
    }
    __syncthreads();

    float w_[16] = {};
    const float* w2 = Wa2 + tid;
#pragma unroll 4
    for (int j = 0; j < 256; ++j) fma16(w_, &buf[j][0], w2[(size_t)j * 256]);
    float bb2 = ba2[tid];
#pragma unroll
    for (int oo = 0; oo < 16; ++oo) w_[oo] += bb2;

    red16<true>(w_, sO, scr);
    float e_[16];
#pragma unroll
    for (int oo = 0; oo < 16; ++oo) e_[oo] = __expf(w_[oo] - sO[oo]);
    red16<false>(e_, sS, scr);
#pragma unroll
    for (int oo = 0; oo < 16; ++oo) tmp[oo] = vv[oo] * e_[oo] / sS[oo];
    red16<false>(tmp, sQ, scr);
    if (tid < 16) out[bs * 128 + o0 + tid] = sQ[tid];
}

// ---------------------------------------------------------------------------
// Launch
// ---------------------------------------------------------------------------
extern "C" void kernel_launch(void* const* d_in, const int* in_sizes, int n_in,
                              void* d_out, int out_size, void* d_ws, size_t ws_size,
                              hipStream_t stream) {
    const float* x      = (const float*)d_in[0];
    const float* ln0_g  = (const float*)d_in[1];
    const float* ln0_b  = (const float*)d_in[2];
    const float* W0     = (const float*)d_in[3];
    const float* b0     = (const float*)d_in[4];
    const float* rln_g  = (const float*)d_in[5];
    const float* rln_b  = (const float*)d_in[6];
    const float* rW     = (const float*)d_in[7];
    const float* rb     = (const float*)d_in[8];
    const float* lnf_g  = (const float*)d_in[9];
    const float* lnf_b  = (const float*)d_in[10];
    const float* Wf     = (const float*)d_in[11];
    const float* bf_    = (const float*)d_in[12];
    const float* ln1_g  = (const float*)d_in[13];
    const float* ln1_b  = (const float*)d_in[14];
    const float* Wa1    = (const float*)d_in[15];
    const float* ba1    = (const float*)d_in[16];
    const float* ln2_g  = (const float*)d_in[17];
    const float* ln2_b  = (const float*)d_in[18];
    const float* Wa2    = (const float*)d_in[19];
    const float* ba2    = (const float*)d_in[20];
    float* out = (float*)d_out;

    const int R = 64 * 256;   // 16384 rows
    float*  h  = (float*)d_ws;                          // R*1024 f32   (64 MB)
    ushort* Ap = (ushort*)(h + (size_t)R * 1024);       // R*1024*2 u16 (64 MB)
    float*  fc = (float*)(Ap + (size_t)R * 2048);       // R*128 f32    (8 MB)
    ushort* Wp = (ushort*)(fc + (size_t)R * 128);       // up to 4 MB

    // stem: h = relu(LN(x) @ W0 + b0)
    conv_w<<<dim3(16, 16), 64, 0, stream>>>(W0, Wp, 512, 1024);
    ln_pack<<<R, 256, 0, stream>>>(x, ln0_g, ln0_b, Ap, 512);
    gemm_mfma256<0><<<dim3(64, 4), 512, 0, stream>>>(Ap, Wp, b0, h, R, 1024, 512);

    // residual blocks
    for (int i = 0; i < 8; ++i) {
        conv_w<<<dim3(16, 32), 64, 0, stream>>>(rW + (size_t)i * 1024 * 1024, Wp, 1024, 1024);
        ln_pack<<<R, 256, 0, stream>>>(h, rln_g + i * 1024, rln_b + i * 1024, Ap, 1024);
        gemm_mfma256<1><<<dim3(64, 4), 512, 0, stream>>>(Ap, Wp, rb + i * 1024, h, R, 1024, 1024);
    }

    // head: fc = LN(h) @ Wf + bf  (N=128 -> proven 128^2 kernel)
    conv_w<<<dim3(2, 32), 64, 0, stream>>>(Wf, Wp, 1024, 128);
    ln_pack<<<R, 256, 0, stream>>>(h, lnf_g, lnf_b, Ap, 1024);
    gemm_mfma<2><<<dim3(128, 1), 256, 0, stream>>>(Ap, Wp, bf_, fc, R, 128, 1024);

    // fused attention + weighted sum (16 outputs per block)
    attn_g16<<<64 * 8, 256, 0, stream>>>(fc, ln1_g, ln1_b, Wa1, ba1,
                                         ln2_g, ln2_b, Wa2, ba2, out);
}